// Round 17
// baseline (30.974 us; speedup 1.0000x reference)
//
#include <hip/hip_runtime.h>
#include <cstdint>

// Problem constants (from setup_inputs: logits/targets [16,1,512,512] f32)
#define BB 16
#define HH 512
#define WW 512
#define NPIX (BB*HH*WW)          // 4194304
#define WR (HH/32)               // 16 word-rows per image
#define NWORDS (BB*WR*WW)        // 131072 u32 = 512 KB
#define NXCD 8
#define RPB 8                    // rows per block (8-aligned base: p0+7 <= 31)
#define NPAIR (RPB/2)            // 4 row-pairs per block
#define NGRP (BB*HH/RPB)         // 1024 blocks
#define GCHUNK (NGRP/NXCD)       // 128

// ---------------------------------------------------------------------------
// Kernel 0: vertical bit-pack of targets, 2 words per thread via float2 loads.
// vmask[b][w][j] bit r = (targets[b][32w+r][j] > 0.5).  512 KB total.
// ---------------------------------------------------------------------------
__global__ __launch_bounds__(256) void packbits(const float* __restrict__ targets,
                                                uint32_t* __restrict__ vmask) {
    const int flat = blockIdx.x * 256 + threadIdx.x;   // 0..65535
    const int jp = (flat & 255) * 2;                   // even column
    const int w  = (flat >> 8) & (WR - 1);
    const int b  = flat >> 12;
    const float2* base =
        (const float2*)(targets + ((size_t)(b * HH + w * 32)) * WW + jp);
    uint32_t w0 = 0, w1 = 0;
    #pragma unroll
    for (int r = 0; r < 32; ++r) {
        const float2 q = base[r * (WW / 2)];
        w0 |= (q.x > 0.5f ? 1u : 0u) << r;
        w1 |= (q.y > 0.5f ? 1u : 0u) << r;
    }
    ((uint2*)vmask)[flat] = make_uint2(w0, w1);        // 2*flat == b*8192+w*512+jp
}

// ---------------------------------------------------------------------------
// Fused kernel: one block per 8-ROW GROUP, 512 threads = one column each.
//  Phase 1: TRANSITION-mask trick: T = X ^ (X>>1) computed ONCE per thread;
//           per row dd = ffs(Td>>p), du = clz(Tu<<(32-p))+1 (first transition
//           == first opposite). Boundary bits masked; exact word-scan
//           fallback (P ~ 2^-32) unchanged.
//  Phase 2: two rows per LDS word (round-16 proven: LDS-issue bound, halve
//           reads); k=1,2 unroll + exact pair-merged divergent tail.
//  Phase 3: p = clip(sigmoid) via rcp; v += p*sqrt(m); block shfl-reduce,
//           then ONE bare atomicAdd per block of the pre-scaled partial
//           (NO threadfence — round-7's stall was the fence chain, not the
//           atomic). out is zeroed by a captured hipMemsetAsync each call.
// ---------------------------------------------------------------------------
__global__ __launch_bounds__(512) void fused_row8(
        const uint32_t* __restrict__ vmask,
        const float* __restrict__ logits,
        float* __restrict__ out) {
    const int bid = blockIdx.x;
    const int g   = (bid & (NXCD - 1)) * GCHUNK + (bid >> 3);  // bijective swizzle
    const int b   = g >> 6;                 // 64 groups per image
    const int i0  = (g & 63) << 3;          // first row of the group (8-aligned)
    const int j   = threadIdx.x;
    const int w   = i0 >> 5;                // shared word-row (i0..i0+7 same word)
    const int p0  = i0 & 31;                // in {0,8,16,24}

    __shared__ uint32_t pk_s[NPAIR][WW];    // 8 KB
    __shared__ float    sw[8];

    const uint32_t* vm = vmask + (size_t)b * WR * WW;

    // one word-column triple serves all 8 rows
    const uint32_t Wse = vm[w * WW + j];
    const bool has_u = (w > 0), has_d = (w < WR - 1);
    const uint32_t Wup = has_u ? vm[(w - 1) * WW + j] : 0u;
    const uint32_t Wdn = has_d ? vm[(w + 1) * WW + j] : 0u;

    // logits for the 8 pixels (independent coalesced loads, overlap phase 1)
    float xs[RPB];
    #pragma unroll
    for (int r = 0; r < RPB; ++r)
        xs[r] = logits[((size_t)(b * HH + i0 + r)) * WW + j];

    // transition masks, computed once per thread:
    // downfull bit q <-> row 32w+q; upfull bit q <-> row 32w-32+q.
    // T bit q set iff rows q and q+1 differ; first transition >= p is the
    // first opposite (dd = ffs(Td>>p)); highest transition < p+32 gives du.
    const uint64_t downfull = (uint64_t)Wse | ((uint64_t)Wdn << 32);
    const uint64_t upfull   = ((uint64_t)Wse << 32) | (uint64_t)Wup;
    const uint64_t Td = (downfull ^ (downfull >> 1)) &
                        (has_d ? 0x7FFFFFFFFFFFFFFFull : 0x000000007FFFFFFFull);
    const uint64_t Tu = (upfull ^ (upfull >> 1)) &
                        (has_u ? 0xFFFFFFFFFFFFFFFFull : 0xFFFFFFFF00000000ull);

    int dpx[RPB], tpx[RPB];
    #pragma unroll
    for (int r = 0; r < RPB; ++r) {
        const int p = p0 + r;               // <= 31 always
        const int i = i0 + r;
        const int t = (int)((Wse >> p) & 1u);

        const uint64_t zd = Td >> p;            // transitions at q >= p
        const uint64_t zu = Tu << (32 - p);     // transitions at q < p+32
        int dd, du;
        if (zd) {
            dd = __ffsll((unsigned long long)zd);
        } else {                                // essentially never
            const uint32_t tm = t ? 0xFFFFFFFFu : 0u;
            dd = 1023;
            for (int ww = w + 2; ww < WR; ++ww) {
                const uint32_t Xw = vm[ww * WW + j] ^ tm;
                if (Xw) { dd = 32 * ww + (__ffs(Xw) - 1) - i; break; }
            }
        }
        if (zu) {
            du = __clzll((long long)zu) + 1;
        } else {                                // essentially never
            const uint32_t tm = t ? 0xFFFFFFFFu : 0u;
            du = 1023;
            for (int ww = w - 2; ww >= 0; --ww) {
                const uint32_t Xw = vm[ww * WW + j] ^ tm;
                if (Xw) { du = i - (32 * ww + 31 - __clz((int)Xw)); break; }
            }
        }
        dpx[r] = min(min(dd, du), 1023);
        tpx[r] = t;
    }

    // pack two rows per LDS word: lo16 = row 2p, hi16 = row 2p+1
    #pragma unroll
    for (int pr = 0; pr < NPAIR; ++pr) {
        const uint32_t lo = (uint32_t)((dpx[2 * pr]     << 1) | tpx[2 * pr]);
        const uint32_t hi = (uint32_t)((dpx[2 * pr + 1] << 1) | tpx[2 * pr + 1]);
        pk_s[pr][j] = lo | (hi << 16);
    }
    __syncthreads();

    // ---- Phase 2: four pair-loops; each ds_read serves two rows ----
    int mpx[RPB];
    #pragma unroll
    for (int pr = 0; pr < NPAIR; ++pr) {
        const int t0 = tpx[2 * pr], t1 = tpx[2 * pr + 1];
        int m0 = dpx[2 * pr] * dpx[2 * pr];
        int m1 = dpx[2 * pr + 1] * dpx[2 * pr + 1];
        const uint32_t* rowp = &pk_s[pr][0];

        #pragma unroll
        for (int k = 1; k <= 2; ++k) {
            const int jl = j - k, jr = j + k;
            const int k2 = k * k;
            const uint32_t pl = rowp[jl >= 0 ? jl : 0];
            const uint32_t pr_ = rowp[jr < WW ? jr : (WW - 1)];
            const int d0l = ((int)(pl & 1u) == t0)          ? (int)((pl & 0xFFFFu) >> 1) : 0;
            const int d1l = ((int)((pl >> 16) & 1u) == t1)  ? (int)(pl >> 17)            : 0;
            const int d0r = ((int)(pr_ & 1u) == t0)         ? (int)((pr_ & 0xFFFFu) >> 1) : 0;
            const int d1r = ((int)((pr_ >> 16) & 1u) == t1) ? (int)(pr_ >> 17)           : 0;
            const int c0l = (jl >= 0) ? (d0l * d0l + k2) : 0x7fffffff;
            const int c1l = (jl >= 0) ? (d1l * d1l + k2) : 0x7fffffff;
            const int c0r = (jr < WW) ? (d0r * d0r + k2) : 0x7fffffff;
            const int c1r = (jr < WW) ? (d1r * d1r + k2) : 0x7fffffff;
            m0 = min(m0, min(c0l, c0r));
            m1 = min(m1, min(c1l, c1r));
        }

        // exact pair-merged divergent tail (avg ~1-3 wave iterations)
        {
            const int kmaxRow = max(j, WW - 1 - j);
            for (int k = 3; k <= kmaxRow && k * k < max(m0, m1); ++k) {
                const int k2 = k * k;
                if (k <= j) {
                    const uint32_t p2 = rowp[j - k];
                    const int e0 = ((int)(p2 & 1u) == t0)         ? (int)((p2 & 0xFFFFu) >> 1) : 0;
                    const int e1 = ((int)((p2 >> 16) & 1u) == t1) ? (int)(p2 >> 17)            : 0;
                    m0 = min(m0, e0 * e0 + k2);
                    m1 = min(m1, e1 * e1 + k2);
                }
                if (k <= WW - 1 - j) {
                    const uint32_t p2 = rowp[j + k];
                    const int e0 = ((int)(p2 & 1u) == t0)         ? (int)((p2 & 0xFFFFu) >> 1) : 0;
                    const int e1 = ((int)((p2 >> 16) & 1u) == t1) ? (int)(p2 >> 17)            : 0;
                    m0 = min(m0, e0 * e0 + k2);
                    m1 = min(m1, e1 * e1 + k2);
                }
            }
        }
        mpx[2 * pr] = m0;
        mpx[2 * pr + 1] = m1;
    }

    // ---- Phase 3: loss terms ----
    float v = 0.0f;
    #pragma unroll
    for (int r = 0; r < RPB; ++r) {
        const float dt = __builtin_amdgcn_sqrtf((float)mpx[r]);
        float pr = __builtin_amdgcn_rcpf(1.0f + __expf(-xs[r]));
        pr = fminf(fmaxf(pr, 1e-7f), (float)(1.0 - 1e-7));
        v += pr * dt;
    }

    // ---- block reduction (512 threads = 8 waves), then one atomic ----
    #pragma unroll
    for (int off = 32; off > 0; off >>= 1)
        v += __shfl_down(v, off);

    const int lane = threadIdx.x & 63;
    const int wid  = threadIdx.x >> 6;
    if (lane == 0) sw[wid] = v;
    __syncthreads();
    if (threadIdx.x == 0) {
        float s = 0.0f;
        #pragma unroll
        for (int ww = 0; ww < 8; ++ww) s += sw[ww];
        atomicAdd(out, s * (1.0f / (float)NPIX));   // bare atomic, no fence
    }
}

extern "C" void kernel_launch(void* const* d_in, const int* in_sizes, int n_in,
                              void* d_out, int out_size, void* d_ws, size_t ws_size,
                              hipStream_t stream) {
    const float* logits  = (const float*)d_in[0];
    const float* targets = (const float*)d_in[1];
    float* out = (float*)d_out;

    // workspace layout: [ vmask u32 NWORDS (512KB) ]
    uint32_t* vmask = (uint32_t*)d_ws;

    hipMemsetAsync(out, 0, sizeof(float), stream);
    packbits<<<NWORDS / 2 / 256, 256, 0, stream>>>(targets, vmask);
    fused_row8<<<NGRP, 512, 0, stream>>>(vmask, logits, out);
}

// Round 18
// 20.766 us; speedup vs baseline: 1.4916x; 1.4916x over previous
//
#include <hip/hip_runtime.h>
#include <cstdint>

// Problem constants (from setup_inputs: logits/targets [16,1,512,512] f32)
#define BB 16
#define HH 512
#define WW 512
#define NPIX (BB*HH*WW)          // 4194304
#define WR (HH/32)               // 16 word-rows per image
#define NWORDS (BB*WR*WW)        // 131072 u32 = 512 KB
#define NXCD 8
#define RPB 8                    // rows per block (8-aligned base: p0+7 <= 31)
#define NPAIR (RPB/2)            // 4 row-pairs per block
#define NGRP (BB*HH/RPB)         // 1024 blocks
#define GCHUNK (NGRP/NXCD)       // 128

// ---------------------------------------------------------------------------
// Kernel 0: vertical bit-pack of targets, 2 words per thread via float2 loads.
// vmask[b][w][j] bit r = (targets[b][32w+r][j] > 0.5).  512 KB total.
// ---------------------------------------------------------------------------
__global__ __launch_bounds__(256) void packbits(const float* __restrict__ targets,
                                                uint32_t* __restrict__ vmask) {
    const int flat = blockIdx.x * 256 + threadIdx.x;   // 0..65535
    const int jp = (flat & 255) * 2;                   // even column
    const int w  = (flat >> 8) & (WR - 1);
    const int b  = flat >> 12;
    const float2* base =
        (const float2*)(targets + ((size_t)(b * HH + w * 32)) * WW + jp);
    uint32_t w0 = 0, w1 = 0;
    #pragma unroll
    for (int r = 0; r < 32; ++r) {
        const float2 q = base[r * (WW / 2)];
        w0 |= (q.x > 0.5f ? 1u : 0u) << r;
        w1 |= (q.y > 0.5f ? 1u : 0u) << r;
    }
    ((uint2*)vmask)[flat] = make_uint2(w0, w1);        // 2*flat == b*8192+w*512+jp
}

// ---------------------------------------------------------------------------
// Fused kernel: one block per 8-ROW GROUP, 512 threads = one column each.
//  Phase 1: TRANSITION-mask trick: T = X ^ (X>>1) computed ONCE per thread;
//           per row dd = ffs(Td>>p), du = clz(Tu<<(32-p))+1 (first transition
//           == first opposite). Boundary bits masked; exact word-scan
//           fallback (P ~ 2^-32) unchanged.
//  Phase 2: two rows per LDS word (round-16 proven: LDS-issue bound, halve
//           reads); k=1,2 unroll + exact pair-merged divergent tail.
//  Phase 3: p = clip(sigmoid) via rcp; v += p*sqrt(m); one reduce / 4096 px
//           into partial[] — NO atomics (round-17: 1024 same-address atomics
//           across 8 XCD L2s cost ~10 us; round-7: per-block fences cost
//           ~175 us. All cross-XCD visibility traffic loses here.)
// ---------------------------------------------------------------------------
__global__ __launch_bounds__(512) void fused_row8(
        const uint32_t* __restrict__ vmask,
        const float* __restrict__ logits,
        float* __restrict__ partial) {
    const int bid = blockIdx.x;
    const int g   = (bid & (NXCD - 1)) * GCHUNK + (bid >> 3);  // bijective swizzle
    const int b   = g >> 6;                 // 64 groups per image
    const int i0  = (g & 63) << 3;          // first row of the group (8-aligned)
    const int j   = threadIdx.x;
    const int w   = i0 >> 5;                // shared word-row (i0..i0+7 same word)
    const int p0  = i0 & 31;                // in {0,8,16,24}

    __shared__ uint32_t pk_s[NPAIR][WW];    // 8 KB
    __shared__ float    sw[8];

    const uint32_t* vm = vmask + (size_t)b * WR * WW;

    // one word-column triple serves all 8 rows
    const uint32_t Wse = vm[w * WW + j];
    const bool has_u = (w > 0), has_d = (w < WR - 1);
    const uint32_t Wup = has_u ? vm[(w - 1) * WW + j] : 0u;
    const uint32_t Wdn = has_d ? vm[(w + 1) * WW + j] : 0u;

    // logits for the 8 pixels (independent coalesced loads, overlap phase 1)
    float xs[RPB];
    #pragma unroll
    for (int r = 0; r < RPB; ++r)
        xs[r] = logits[((size_t)(b * HH + i0 + r)) * WW + j];

    // transition masks, computed once per thread:
    // downfull bit q <-> row 32w+q; upfull bit q <-> row 32w-32+q.
    // T bit q set iff rows q and q+1 differ; first transition >= p is the
    // first opposite (dd = ffs(Td>>p)); highest transition < p+32 gives du.
    const uint64_t downfull = (uint64_t)Wse | ((uint64_t)Wdn << 32);
    const uint64_t upfull   = ((uint64_t)Wse << 32) | (uint64_t)Wup;
    const uint64_t Td = (downfull ^ (downfull >> 1)) &
                        (has_d ? 0x7FFFFFFFFFFFFFFFull : 0x000000007FFFFFFFull);
    const uint64_t Tu = (upfull ^ (upfull >> 1)) &
                        (has_u ? 0xFFFFFFFFFFFFFFFFull : 0xFFFFFFFF00000000ull);

    int dpx[RPB], tpx[RPB];
    #pragma unroll
    for (int r = 0; r < RPB; ++r) {
        const int p = p0 + r;               // <= 31 always
        const int i = i0 + r;
        const int t = (int)((Wse >> p) & 1u);

        const uint64_t zd = Td >> p;            // transitions at q >= p
        const uint64_t zu = Tu << (32 - p);     // transitions at q < p+32
        int dd, du;
        if (zd) {
            dd = __ffsll((unsigned long long)zd);
        } else {                                // essentially never
            const uint32_t tm = t ? 0xFFFFFFFFu : 0u;
            dd = 1023;
            for (int ww = w + 2; ww < WR; ++ww) {
                const uint32_t Xw = vm[ww * WW + j] ^ tm;
                if (Xw) { dd = 32 * ww + (__ffs(Xw) - 1) - i; break; }
            }
        }
        if (zu) {
            du = __clzll((long long)zu) + 1;
        } else {                                // essentially never
            const uint32_t tm = t ? 0xFFFFFFFFu : 0u;
            du = 1023;
            for (int ww = w - 2; ww >= 0; --ww) {
                const uint32_t Xw = vm[ww * WW + j] ^ tm;
                if (Xw) { du = i - (32 * ww + 31 - __clz((int)Xw)); break; }
            }
        }
        dpx[r] = min(min(dd, du), 1023);
        tpx[r] = t;
    }

    // pack two rows per LDS word: lo16 = row 2p, hi16 = row 2p+1
    #pragma unroll
    for (int pr = 0; pr < NPAIR; ++pr) {
        const uint32_t lo = (uint32_t)((dpx[2 * pr]     << 1) | tpx[2 * pr]);
        const uint32_t hi = (uint32_t)((dpx[2 * pr + 1] << 1) | tpx[2 * pr + 1]);
        pk_s[pr][j] = lo | (hi << 16);
    }
    __syncthreads();

    // ---- Phase 2: four pair-loops; each ds_read serves two rows ----
    int mpx[RPB];
    #pragma unroll
    for (int pr = 0; pr < NPAIR; ++pr) {
        const int t0 = tpx[2 * pr], t1 = tpx[2 * pr + 1];
        int m0 = dpx[2 * pr] * dpx[2 * pr];
        int m1 = dpx[2 * pr + 1] * dpx[2 * pr + 1];
        const uint32_t* rowp = &pk_s[pr][0];

        #pragma unroll
        for (int k = 1; k <= 2; ++k) {
            const int jl = j - k, jr = j + k;
            const int k2 = k * k;
            const uint32_t pl = rowp[jl >= 0 ? jl : 0];
            const uint32_t pr_ = rowp[jr < WW ? jr : (WW - 1)];
            const int d0l = ((int)(pl & 1u) == t0)          ? (int)((pl & 0xFFFFu) >> 1) : 0;
            const int d1l = ((int)((pl >> 16) & 1u) == t1)  ? (int)(pl >> 17)            : 0;
            const int d0r = ((int)(pr_ & 1u) == t0)         ? (int)((pr_ & 0xFFFFu) >> 1) : 0;
            const int d1r = ((int)((pr_ >> 16) & 1u) == t1) ? (int)(pr_ >> 17)           : 0;
            const int c0l = (jl >= 0) ? (d0l * d0l + k2) : 0x7fffffff;
            const int c1l = (jl >= 0) ? (d1l * d1l + k2) : 0x7fffffff;
            const int c0r = (jr < WW) ? (d0r * d0r + k2) : 0x7fffffff;
            const int c1r = (jr < WW) ? (d1r * d1r + k2) : 0x7fffffff;
            m0 = min(m0, min(c0l, c0r));
            m1 = min(m1, min(c1l, c1r));
        }

        // exact pair-merged divergent tail (avg ~1-3 wave iterations)
        {
            const int kmaxRow = max(j, WW - 1 - j);
            for (int k = 3; k <= kmaxRow && k * k < max(m0, m1); ++k) {
                const int k2 = k * k;
                if (k <= j) {
                    const uint32_t p2 = rowp[j - k];
                    const int e0 = ((int)(p2 & 1u) == t0)         ? (int)((p2 & 0xFFFFu) >> 1) : 0;
                    const int e1 = ((int)((p2 >> 16) & 1u) == t1) ? (int)(p2 >> 17)            : 0;
                    m0 = min(m0, e0 * e0 + k2);
                    m1 = min(m1, e1 * e1 + k2);
                }
                if (k <= WW - 1 - j) {
                    const uint32_t p2 = rowp[j + k];
                    const int e0 = ((int)(p2 & 1u) == t0)         ? (int)((p2 & 0xFFFFu) >> 1) : 0;
                    const int e1 = ((int)((p2 >> 16) & 1u) == t1) ? (int)(p2 >> 17)            : 0;
                    m0 = min(m0, e0 * e0 + k2);
                    m1 = min(m1, e1 * e1 + k2);
                }
            }
        }
        mpx[2 * pr] = m0;
        mpx[2 * pr + 1] = m1;
    }

    // ---- Phase 3: loss terms ----
    float v = 0.0f;
    #pragma unroll
    for (int r = 0; r < RPB; ++r) {
        const float dt = __builtin_amdgcn_sqrtf((float)mpx[r]);
        float pr = __builtin_amdgcn_rcpf(1.0f + __expf(-xs[r]));
        pr = fminf(fmaxf(pr, 1e-7f), (float)(1.0 - 1e-7));
        v += pr * dt;
    }

    // ---- block reduction (512 threads = 8 waves), one per 4096 px ----
    #pragma unroll
    for (int off = 32; off > 0; off >>= 1)
        v += __shfl_down(v, off);

    const int lane = threadIdx.x & 63;
    const int wid  = threadIdx.x >> 6;
    if (lane == 0) sw[wid] = v;
    __syncthreads();
    if (threadIdx.x == 0) {
        float s = 0.0f;
        #pragma unroll
        for (int ww = 0; ww < 8; ++ww) s += sw[ww];
        partial[g] = s;
    }
}

// ---------------------------------------------------------------------------
// Deterministic final reduction of NGRP partials -> mean
// ---------------------------------------------------------------------------
__global__ __launch_bounds__(256) void finalreduce(
        const float* __restrict__ partial,
        float* __restrict__ out) {
    const float4 q = ((const float4*)partial)[threadIdx.x];   // 256*4 == 1024
    float v = (q.x + q.y) + (q.z + q.w);

    #pragma unroll
    for (int off = 32; off > 0; off >>= 1)
        v += __shfl_down(v, off);

    __shared__ float sw[4];
    const int lane = threadIdx.x & 63;
    const int wid  = threadIdx.x >> 6;
    if (lane == 0) sw[wid] = v;
    __syncthreads();
    if (threadIdx.x == 0)
        out[0] = ((sw[0] + sw[1]) + (sw[2] + sw[3])) * (1.0f / (float)NPIX);
}

extern "C" void kernel_launch(void* const* d_in, const int* in_sizes, int n_in,
                              void* d_out, int out_size, void* d_ws, size_t ws_size,
                              hipStream_t stream) {
    const float* logits  = (const float*)d_in[0];
    const float* targets = (const float*)d_in[1];
    float* out = (float*)d_out;

    // workspace layout: [ vmask u32 NWORDS (512KB) | partial float NGRP (4KB) ]
    uint32_t* vmask = (uint32_t*)d_ws;
    float* partial  = (float*)((char*)d_ws + (size_t)NWORDS * sizeof(uint32_t));

    packbits<<<NWORDS / 2 / 256, 256, 0, stream>>>(targets, vmask);
    fused_row8<<<NGRP, 512, 0, stream>>>(vmask, logits, partial);
    finalreduce<<<1, 256, 0, stream>>>(partial, out);
}

// Round 19
// 20.677 us; speedup vs baseline: 1.4980x; 1.0043x over previous
//
#include <hip/hip_runtime.h>
#include <cstdint>

// Problem constants (from setup_inputs: logits/targets [16,1,512,512] f32)
#define BB 16
#define HH 512
#define WW 512
#define NPIX (BB*HH*WW)          // 4194304
#define NBLK 256                 // one block per 32-row word-group (16 img x 16)
#define NXCD 8

// ---------------------------------------------------------------------------
// Single fused kernel: one block per 32-ROW WORD-GROUP, 512 threads = one
// column each, 32 pixels per thread in 4 chunks of 8 rows.
//  Mask build: each thread builds Wse/Wup/Wdn itself from targets (96
//    coalesced loads, 3 loads/px) — the packbits dispatch and its launch gap
//    are gone; the targets HBM read overlaps compute.
//  Phase 1: transition masks Td/Tu computed ONCE serve all 32 rows;
//    per row dd = ffs(Td>>p), du = clz(Tu<<(32-p))+1. Fallback beyond the
//    64-bit window: direct column scan of targets (P ~ 2^-32, exact).
//  Phase 2 (per chunk): two rows per LDS word (round-16 proven: LDS-issue
//    bound), k=1,2 unroll + exact pair-merged divergent tail.
//  Phase 3: p = clip(sigmoid) via rcp; v += p*sqrt(m); one block reduce at
//    the very end -> partial[256]. NO atomics/fences (rounds 7/17 lessons).
// ---------------------------------------------------------------------------
__global__ __launch_bounds__(512) void fused32(
        const float* __restrict__ targets,
        const float* __restrict__ logits,
        float* __restrict__ partial) {
    const int bid = blockIdx.x;
    const int g   = (bid & (NXCD - 1)) * (NBLK / NXCD) + (bid >> 3);  // bijective
    const int b   = g >> 4;                 // image
    const int w   = g & 15;                 // word-row within image
    const int i0  = w << 5;                 // first row of the group
    const int j   = threadIdx.x;

    __shared__ uint32_t pk_s[4][WW];        // 8 KB, reused per chunk
    __shared__ float    sw[8];

    const float* tcol = targets + (size_t)b * HH * WW + j;
    const float* lcol = logits  + (size_t)b * HH * WW + j;
    const bool has_u = (w > 0), has_d = (w < 15);

    // build the three 32-bit vertical masks for this column (coalesced loads)
    uint32_t Wse = 0u, Wup = 0u, Wdn = 0u;
    #pragma unroll
    for (int r = 0; r < 32; ++r)
        Wse |= (tcol[(i0 + r) * WW] > 0.5f ? 1u : 0u) << r;
    if (has_u) {
        #pragma unroll
        for (int r = 0; r < 32; ++r)
            Wup |= (tcol[(i0 - 32 + r) * WW] > 0.5f ? 1u : 0u) << r;
    }
    if (has_d) {
        #pragma unroll
        for (int r = 0; r < 32; ++r)
            Wdn |= (tcol[(i0 + 32 + r) * WW] > 0.5f ? 1u : 0u) << r;
    }

    // transition masks, once per thread, serving all 32 rows:
    // downfull bit q <-> row 32w+q; upfull bit q <-> row 32w-32+q.
    const uint64_t downfull = (uint64_t)Wse | ((uint64_t)Wdn << 32);
    const uint64_t upfull   = ((uint64_t)Wse << 32) | (uint64_t)Wup;
    const uint64_t Td = (downfull ^ (downfull >> 1)) &
                        (has_d ? 0x7FFFFFFFFFFFFFFFull : 0x000000007FFFFFFFull);
    const uint64_t Tu = (upfull ^ (upfull >> 1)) &
                        (has_u ? 0xFFFFFFFFFFFFFFFFull : 0xFFFFFFFF00000000ull);

    float v = 0.0f;

    for (int c = 0; c < 4; ++c) {           // 4 chunks x 8 rows
        const int p0 = c << 3;

        // logits for this chunk (coalesced, overlap phase 1)
        float xs[8];
        #pragma unroll
        for (int r = 0; r < 8; ++r)
            xs[r] = lcol[(i0 + p0 + r) * WW];

        int dpx[8], tpx[8];
        #pragma unroll
        for (int r = 0; r < 8; ++r) {
            const int p = p0 + r;           // 0..31
            const int i = i0 + p;
            const int t = (int)((Wse >> p) & 1u);
            const uint64_t zd = Td >> p;            // transitions at q >= p
            const uint64_t zu = Tu << (32 - p);     // transitions below row i
            int dd, du;
            if (zd) {
                dd = __ffsll((unsigned long long)zd);
            } else {                        // essentially never: direct scan
                dd = 1023;
                for (int i2 = 32 * w + 64; i2 < HH; ++i2) {
                    const int t2 = tcol[i2 * WW] > 0.5f ? 1 : 0;
                    if (t2 != t) { dd = i2 - i; break; }
                }
            }
            if (zu) {
                du = __clzll((long long)zu) + 1;
            } else {                        // essentially never: direct scan
                du = 1023;
                for (int i2 = 32 * w - 33; i2 >= 0; --i2) {
                    const int t2 = tcol[i2 * WW] > 0.5f ? 1 : 0;
                    if (t2 != t) { du = i - i2; break; }
                }
            }
            dpx[r] = min(min(dd, du), 1023);
            tpx[r] = t;
        }

        // pack two rows per LDS word: lo16 = row 2pr, hi16 = row 2pr+1
        #pragma unroll
        for (int pr = 0; pr < 4; ++pr) {
            const uint32_t lo = (uint32_t)((dpx[2 * pr]     << 1) | tpx[2 * pr]);
            const uint32_t hi = (uint32_t)((dpx[2 * pr + 1] << 1) | tpx[2 * pr + 1]);
            pk_s[pr][j] = lo | (hi << 16);
        }
        __syncthreads();

        // ---- Phase 2: four pair-loops; each ds_read serves two rows ----
        int mpx[8];
        #pragma unroll
        for (int pr = 0; pr < 4; ++pr) {
            const int t0 = tpx[2 * pr], t1 = tpx[2 * pr + 1];
            int m0 = dpx[2 * pr] * dpx[2 * pr];
            int m1 = dpx[2 * pr + 1] * dpx[2 * pr + 1];
            const uint32_t* rowp = &pk_s[pr][0];

            #pragma unroll
            for (int k = 1; k <= 2; ++k) {
                const int jl = j - k, jr = j + k;
                const int k2 = k * k;
                const uint32_t pl  = rowp[jl >= 0 ? jl : 0];
                const uint32_t pr_ = rowp[jr < WW ? jr : (WW - 1)];
                const int d0l = ((int)(pl & 1u) == t0)          ? (int)((pl & 0xFFFFu) >> 1)  : 0;
                const int d1l = ((int)((pl >> 16) & 1u) == t1)  ? (int)(pl >> 17)             : 0;
                const int d0r = ((int)(pr_ & 1u) == t0)         ? (int)((pr_ & 0xFFFFu) >> 1) : 0;
                const int d1r = ((int)((pr_ >> 16) & 1u) == t1) ? (int)(pr_ >> 17)            : 0;
                const int c0l = (jl >= 0) ? (d0l * d0l + k2) : 0x7fffffff;
                const int c1l = (jl >= 0) ? (d1l * d1l + k2) : 0x7fffffff;
                const int c0r = (jr < WW) ? (d0r * d0r + k2) : 0x7fffffff;
                const int c1r = (jr < WW) ? (d1r * d1r + k2) : 0x7fffffff;
                m0 = min(m0, min(c0l, c0r));
                m1 = min(m1, min(c1l, c1r));
            }

            // exact pair-merged divergent tail (avg ~1-3 wave iterations)
            {
                const int kmaxRow = max(j, WW - 1 - j);
                for (int k = 3; k <= kmaxRow && k * k < max(m0, m1); ++k) {
                    const int k2 = k * k;
                    if (k <= j) {
                        const uint32_t p2 = rowp[j - k];
                        const int e0 = ((int)(p2 & 1u) == t0)         ? (int)((p2 & 0xFFFFu) >> 1) : 0;
                        const int e1 = ((int)((p2 >> 16) & 1u) == t1) ? (int)(p2 >> 17)            : 0;
                        m0 = min(m0, e0 * e0 + k2);
                        m1 = min(m1, e1 * e1 + k2);
                    }
                    if (k <= WW - 1 - j) {
                        const uint32_t p2 = rowp[j + k];
                        const int e0 = ((int)(p2 & 1u) == t0)         ? (int)((p2 & 0xFFFFu) >> 1) : 0;
                        const int e1 = ((int)((p2 >> 16) & 1u) == t1) ? (int)(p2 >> 17)            : 0;
                        m0 = min(m0, e0 * e0 + k2);
                        m1 = min(m1, e1 * e1 + k2);
                    }
                }
            }
            mpx[2 * pr]     = m0;
            mpx[2 * pr + 1] = m1;
        }
        __syncthreads();                    // pk_s reused by next chunk

        // ---- Phase 3: loss terms for this chunk ----
        #pragma unroll
        for (int r = 0; r < 8; ++r) {
            const float dt = __builtin_amdgcn_sqrtf((float)mpx[r]);
            float pr = __builtin_amdgcn_rcpf(1.0f + __expf(-xs[r]));
            pr = fminf(fmaxf(pr, 1e-7f), (float)(1.0 - 1e-7));
            v += pr * dt;
        }
    }

    // ---- block reduction (512 threads = 8 waves), once per 16384 px ----
    #pragma unroll
    for (int off = 32; off > 0; off >>= 1)
        v += __shfl_down(v, off);

    const int lane = threadIdx.x & 63;
    const int wid  = threadIdx.x >> 6;
    if (lane == 0) sw[wid] = v;
    __syncthreads();
    if (threadIdx.x == 0) {
        float s = 0.0f;
        #pragma unroll
        for (int ww = 0; ww < 8; ++ww) s += sw[ww];
        partial[g] = s;
    }
}

// ---------------------------------------------------------------------------
// Deterministic final reduction of NBLK (256) partials -> mean (one wave)
// ---------------------------------------------------------------------------
__global__ __launch_bounds__(64) void finalreduce(
        const float* __restrict__ partial,
        float* __restrict__ out) {
    const float4 q = ((const float4*)partial)[threadIdx.x];   // 64*4 == 256
    float v = (q.x + q.y) + (q.z + q.w);

    #pragma unroll
    for (int off = 32; off > 0; off >>= 1)
        v += __shfl_down(v, off);

    if (threadIdx.x == 0)
        out[0] = v * (1.0f / (float)NPIX);
}

extern "C" void kernel_launch(void* const* d_in, const int* in_sizes, int n_in,
                              void* d_out, int out_size, void* d_ws, size_t ws_size,
                              hipStream_t stream) {
    const float* logits  = (const float*)d_in[0];
    const float* targets = (const float*)d_in[1];
    float* out = (float*)d_out;

    float* partial = (float*)d_ws;          // 256 floats

    fused32<<<NBLK, 512, 0, stream>>>(targets, logits, partial);
    finalreduce<<<1, 64, 0, stream>>>(partial, out);
}

// Round 20
// 20.131 us; speedup vs baseline: 1.5386x; 1.0271x over previous
//
#include <hip/hip_runtime.h>
#include <cstdint>

// Problem constants (from setup_inputs: logits/targets [16,1,512,512] f32)
#define BB 16
#define HH 512
#define WW 512
#define NPIX (BB*HH*WW)          // 4194304
#define WR (HH/32)               // 16 word-rows per image
#define NWORDS (BB*WR*WW)        // 131072 u32 = 512 KB
#define NXCD 8
#define RPB 8                    // rows per block (8-aligned base: p0+7 <= 31)
#define NPAIR (RPB/2)            // 4 row-pairs per block
#define NGRP (BB*HH/RPB)         // 1024 blocks
#define GCHUNK (NGRP/NXCD)       // 128

// ---------------------------------------------------------------------------
// Kernel 0: vertical bit-pack of targets, 2 words per thread via float2 loads.
// vmask[b][w][j] bit r = (targets[b][32w+r][j] > 0.5).  512 KB total.
// ---------------------------------------------------------------------------
__global__ __launch_bounds__(256) void packbits(const float* __restrict__ targets,
                                                uint32_t* __restrict__ vmask) {
    const int flat = blockIdx.x * 256 + threadIdx.x;   // 0..65535
    const int jp = (flat & 255) * 2;                   // even column
    const int w  = (flat >> 8) & (WR - 1);
    const int b  = flat >> 12;
    const float2* base =
        (const float2*)(targets + ((size_t)(b * HH + w * 32)) * WW + jp);
    uint32_t w0 = 0, w1 = 0;
    #pragma unroll
    for (int r = 0; r < 32; ++r) {
        const float2 q = base[r * (WW / 2)];
        w0 |= (q.x > 0.5f ? 1u : 0u) << r;
        w1 |= (q.y > 0.5f ? 1u : 0u) << r;
    }
    ((uint2*)vmask)[flat] = make_uint2(w0, w1);        // 2*flat == b*8192+w*512+jp
}

// ---------------------------------------------------------------------------
// Fused kernel: one block per 8-ROW GROUP, 512 threads = one column each.
//  Phase 1: transition-mask trick (T = X ^ (X>>1) once per thread); per row
//           dd = ffs(Td>>p), du = clz(Tu<<(32-p))+1; exact word-scan fallback.
//  Phase 2: PAIR-MAJOR LDS layout pk_s[column] = uint4 of 4 pair-words
//           (lo16/hi16 per pair = (d<<1)|t). ONE ds_read_b128 fetches all
//           8 rows' data of a neighbor column (round-14/16 lesson: phase 2
//           is LDS-issue/latency bound — 4 b128 replace 16 b32 for k=1,2).
//           Tail merged across all 8 rows: while k^2 < max_r m[r], 2 b128
//           reads per iteration (exact: candidates cost >= k^2).
//  Phase 3: p = clip(sigmoid) via rcp; v += p*sqrt(m); one reduce / 4096 px.
// No atomics/fences (rounds 7/17: all cross-XCD visibility traffic loses).
// ---------------------------------------------------------------------------
__global__ __launch_bounds__(512) void fused_row8(
        const uint32_t* __restrict__ vmask,
        const float* __restrict__ logits,
        float* __restrict__ partial) {
    const int bid = blockIdx.x;
    const int g   = (bid & (NXCD - 1)) * GCHUNK + (bid >> 3);  // bijective swizzle
    const int b   = g >> 6;                 // 64 groups per image
    const int i0  = (g & 63) << 3;          // first row of the group (8-aligned)
    const int j   = threadIdx.x;
    const int w   = i0 >> 5;                // shared word-row (i0..i0+7 same word)
    const int p0  = i0 & 31;                // in {0,8,16,24}

    __shared__ uint4 pk_s[WW];              // 8 KB: [column] -> 4 pair-words
    __shared__ float sw[8];

    const uint32_t* vm = vmask + (size_t)b * WR * WW;

    // one word-column triple serves all 8 rows
    const uint32_t Wse = vm[w * WW + j];
    const bool has_u = (w > 0), has_d = (w < WR - 1);
    const uint32_t Wup = has_u ? vm[(w - 1) * WW + j] : 0u;
    const uint32_t Wdn = has_d ? vm[(w + 1) * WW + j] : 0u;

    // logits for the 8 pixels (independent coalesced loads, overlap phase 1)
    float xs[RPB];
    #pragma unroll
    for (int r = 0; r < RPB; ++r)
        xs[r] = logits[((size_t)(b * HH + i0 + r)) * WW + j];

    // transition masks, once per thread (first transition == first opposite)
    const uint64_t downfull = (uint64_t)Wse | ((uint64_t)Wdn << 32);
    const uint64_t upfull   = ((uint64_t)Wse << 32) | (uint64_t)Wup;
    const uint64_t Td = (downfull ^ (downfull >> 1)) &
                        (has_d ? 0x7FFFFFFFFFFFFFFFull : 0x000000007FFFFFFFull);
    const uint64_t Tu = (upfull ^ (upfull >> 1)) &
                        (has_u ? 0xFFFFFFFFFFFFFFFFull : 0xFFFFFFFF00000000ull);

    int dpx[RPB], tpx[RPB];
    #pragma unroll
    for (int r = 0; r < RPB; ++r) {
        const int p = p0 + r;               // <= 31 always
        const int i = i0 + r;
        const int t = (int)((Wse >> p) & 1u);

        const uint64_t zd = Td >> p;            // transitions at q >= p
        const uint64_t zu = Tu << (32 - p);     // transitions below row i
        int dd, du;
        if (zd) {
            dd = __ffsll((unsigned long long)zd);
        } else {                                // essentially never
            const uint32_t tm = t ? 0xFFFFFFFFu : 0u;
            dd = 1023;
            for (int ww = w + 2; ww < WR; ++ww) {
                const uint32_t Xw = vm[ww * WW + j] ^ tm;
                if (Xw) { dd = 32 * ww + (__ffs(Xw) - 1) - i; break; }
            }
        }
        if (zu) {
            du = __clzll((long long)zu) + 1;
        } else {                                // essentially never
            const uint32_t tm = t ? 0xFFFFFFFFu : 0u;
            du = 1023;
            for (int ww = w - 2; ww >= 0; --ww) {
                const uint32_t Xw = vm[ww * WW + j] ^ tm;
                if (Xw) { du = i - (32 * ww + 31 - __clz((int)Xw)); break; }
            }
        }
        dpx[r] = min(min(dd, du), 1023);
        tpx[r] = t;
    }

    // pack: pair-major uint4 per column, one ds_write_b128
    pk_s[j] = make_uint4(
        (uint32_t)((dpx[0] << 1) | tpx[0]) | ((uint32_t)((dpx[1] << 1) | tpx[1]) << 16),
        (uint32_t)((dpx[2] << 1) | tpx[2]) | ((uint32_t)((dpx[3] << 1) | tpx[3]) << 16),
        (uint32_t)((dpx[4] << 1) | tpx[4]) | ((uint32_t)((dpx[5] << 1) | tpx[5]) << 16),
        (uint32_t)((dpx[6] << 1) | tpx[6]) | ((uint32_t)((dpx[7] << 1) | tpx[7]) << 16));
    __syncthreads();

    // helper: fold one neighbor column (uint4) into all 8 rows' minima
    int mpx[RPB];
    #pragma unroll
    for (int r = 0; r < RPB; ++r) mpx[r] = dpx[r] * dpx[r];

    #define FOLD(COL, K2)                                                        \
        do {                                                                     \
            const uint4 _c = (COL);                                              \
            const uint32_t _w[4] = {_c.x, _c.y, _c.z, _c.w};                     \
            _Pragma("unroll")                                                    \
            for (int _pr = 0; _pr < NPAIR; ++_pr) {                              \
                const uint32_t _pk = _w[_pr];                                    \
                const int _e0 = ((int)(_pk & 1u) == tpx[2 * _pr])                \
                                    ? (int)((_pk & 0xFFFFu) >> 1) : 0;           \
                const int _e1 = ((int)((_pk >> 16) & 1u) == tpx[2 * _pr + 1])    \
                                    ? (int)(_pk >> 17) : 0;                      \
                mpx[2 * _pr]     = min(mpx[2 * _pr],     _e0 * _e0 + (K2));      \
                mpx[2 * _pr + 1] = min(mpx[2 * _pr + 1], _e1 * _e1 + (K2));      \
            }                                                                    \
        } while (0)

    // ---- Phase 2: k=1,2 unrolled — 4 ds_read_b128 total ----
    #pragma unroll
    for (int k = 1; k <= 2; ++k) {
        const int jl = j - k, jr = j + k;
        const uint4 pl  = pk_s[jl >= 0 ? jl : 0];
        const uint4 pr_ = pk_s[jr < WW ? jr : (WW - 1)];
        if (jl >= 0) FOLD(pl, k * k);
        if (jr < WW) FOLD(pr_, k * k);
    }

    // ---- merged exact tail over all 8 rows (P ~ 10%/wave, 1-2 iters) ----
    {
        int mx = mpx[0];
        #pragma unroll
        for (int r = 1; r < RPB; ++r) mx = max(mx, mpx[r]);
        const int kmaxRow = max(j, WW - 1 - j);
        for (int k = 3; k <= kmaxRow && k * k < mx; ++k) {
            const int k2 = k * k;
            if (k <= j)          FOLD(pk_s[j - k], k2);
            if (k <= WW - 1 - j) FOLD(pk_s[j + k], k2);
            mx = mpx[0];
            #pragma unroll
            for (int r = 1; r < RPB; ++r) mx = max(mx, mpx[r]);
        }
    }
    #undef FOLD

    // ---- Phase 3: loss terms ----
    float v = 0.0f;
    #pragma unroll
    for (int r = 0; r < RPB; ++r) {
        const float dt = __builtin_amdgcn_sqrtf((float)mpx[r]);
        float pr = __builtin_amdgcn_rcpf(1.0f + __expf(-xs[r]));
        pr = fminf(fmaxf(pr, 1e-7f), (float)(1.0 - 1e-7));
        v += pr * dt;
    }

    // ---- block reduction (512 threads = 8 waves), one per 4096 px ----
    #pragma unroll
    for (int off = 32; off > 0; off >>= 1)
        v += __shfl_down(v, off);

    const int lane = threadIdx.x & 63;
    const int wid  = threadIdx.x >> 6;
    if (lane == 0) sw[wid] = v;
    __syncthreads();
    if (threadIdx.x == 0) {
        float s = 0.0f;
        #pragma unroll
        for (int ww = 0; ww < 8; ++ww) s += sw[ww];
        partial[g] = s;
    }
}

// ---------------------------------------------------------------------------
// Deterministic final reduction of NGRP partials -> mean
// ---------------------------------------------------------------------------
__global__ __launch_bounds__(256) void finalreduce(
        const float* __restrict__ partial,
        float* __restrict__ out) {
    const float4 q = ((const float4*)partial)[threadIdx.x];   // 256*4 == 1024
    float v = (q.x + q.y) + (q.z + q.w);

    #pragma unroll
    for (int off = 32; off > 0; off >>= 1)
        v += __shfl_down(v, off);

    __shared__ float sw[4];
    const int lane = threadIdx.x & 63;
    const int wid  = threadIdx.x >> 6;
    if (lane == 0) sw[wid] = v;
    __syncthreads();
    if (threadIdx.x == 0)
        out[0] = ((sw[0] + sw[1]) + (sw[2] + sw[3])) * (1.0f / (float)NPIX);
}

extern "C" void kernel_launch(void* const* d_in, const int* in_sizes, int n_in,
                              void* d_out, int out_size, void* d_ws, size_t ws_size,
                              hipStream_t stream) {
    const float* logits  = (const float*)d_in[0];
    const float* targets = (const float*)d_in[1];
    float* out = (float*)d_out;

    // workspace layout: [ vmask u32 NWORDS (512KB) | partial float NGRP (4KB) ]
    uint32_t* vmask = (uint32_t*)d_ws;
    float* partial  = (float*)((char*)d_ws + (size_t)NWORDS * sizeof(uint32_t));

    packbits<<<NWORDS / 2 / 256, 256, 0, stream>>>(targets, vmask);
    fused_row8<<<NGRP, 512, 0, stream>>>(vmask, logits, partial);
    finalreduce<<<1, 256, 0, stream>>>(partial, out);
}

// Round 21
// 19.965 us; speedup vs baseline: 1.5514x; 1.0083x over previous
//
#include <hip/hip_runtime.h>
#include <cstdint>

// Problem constants (from setup_inputs: logits/targets [16,1,512,512] f32)
#define BB 16
#define HH 512
#define WW 512
#define NPIX (BB*HH*WW)          // 4194304
#define WR (HH/32)               // 16 word-rows per image
#define NWORDS (BB*WR*WW)        // 131072 u32 = 512 KB
#define NXCD 8
#define RPB 8                    // rows per block (8-aligned base: p0+7 <= 31)
#define NPAIR (RPB/2)            // 4 row-pairs per block
#define NGRP (BB*HH/RPB)         // 1024 blocks
#define GCHUNK (NGRP/NXCD)       // 128

// ---------------------------------------------------------------------------
// Kernel 0: vertical bit-pack of targets, 4 words per thread via float4 loads
// (8 load-insts per output word vs 16 with float2; BW-bound either way).
// vmask[b][w][j] bit r = (targets[b][32w+r][j] > 0.5).  512 KB total.
// ---------------------------------------------------------------------------
__global__ __launch_bounds__(256) void packbits(const float* __restrict__ targets,
                                                uint32_t* __restrict__ vmask) {
    const int flat = blockIdx.x * 256 + threadIdx.x;   // 0..32767
    const int jp = (flat & 127) * 4;                   // 4-aligned column
    const int w  = (flat >> 7) & (WR - 1);
    const int b  = flat >> 11;
    const float4* base =
        (const float4*)(targets + ((size_t)(b * HH + w * 32)) * WW + jp);
    uint32_t w0 = 0, w1 = 0, w2 = 0, w3 = 0;
    #pragma unroll
    for (int r = 0; r < 32; ++r) {
        const float4 q = base[r * (WW / 4)];
        w0 |= (q.x > 0.5f ? 1u : 0u) << r;
        w1 |= (q.y > 0.5f ? 1u : 0u) << r;
        w2 |= (q.z > 0.5f ? 1u : 0u) << r;
        w3 |= (q.w > 0.5f ? 1u : 0u) << r;
    }
    ((uint4*)vmask)[flat] = make_uint4(w0, w1, w2, w3);  // 4*flat == b*8192+w*512+jp
}

// ---------------------------------------------------------------------------
// Fused kernel: one block per 8-ROW GROUP, 512 threads = one column each.
//  Phase 1: transition-mask trick (T = X ^ (X>>1) once per thread); per row
//           dd = ffs(Td>>p), du = clz(Tu<<(32-p))+1; exact word-scan fallback.
//  Phase 2: PAIR-MAJOR LDS layout pk_s[column] = uint4 of 4 pair-words
//           (lo16/hi16 per pair = (d<<1)|t). ONE ds_read_b128 fetches all
//           8 rows' data of a neighbor column. k=1,2 unroll (4 b128) +
//           merged exact tail while k^2 < max_r m[r].
//  Phase 3: p = clip(sigmoid) via rcp; v += p*sqrt(m); one reduce / 4096 px.
// No atomics/fences (rounds 7/17: all cross-XCD visibility traffic loses).
// ---------------------------------------------------------------------------
__global__ __launch_bounds__(512) void fused_row8(
        const uint32_t* __restrict__ vmask,
        const float* __restrict__ logits,
        float* __restrict__ partial) {
    const int bid = blockIdx.x;
    const int g   = (bid & (NXCD - 1)) * GCHUNK + (bid >> 3);  // bijective swizzle
    const int b   = g >> 6;                 // 64 groups per image
    const int i0  = (g & 63) << 3;          // first row of the group (8-aligned)
    const int j   = threadIdx.x;
    const int w   = i0 >> 5;                // shared word-row (i0..i0+7 same word)
    const int p0  = i0 & 31;                // in {0,8,16,24}

    __shared__ uint4 pk_s[WW];              // 8 KB: [column] -> 4 pair-words
    __shared__ float sw[8];

    const uint32_t* vm = vmask + (size_t)b * WR * WW;

    // one word-column triple serves all 8 rows
    const uint32_t Wse = vm[w * WW + j];
    const bool has_u = (w > 0), has_d = (w < WR - 1);
    const uint32_t Wup = has_u ? vm[(w - 1) * WW + j] : 0u;
    const uint32_t Wdn = has_d ? vm[(w + 1) * WW + j] : 0u;

    // logits for the 8 pixels (independent coalesced loads, overlap phase 1)
    float xs[RPB];
    #pragma unroll
    for (int r = 0; r < RPB; ++r)
        xs[r] = logits[((size_t)(b * HH + i0 + r)) * WW + j];

    // transition masks, once per thread (first transition == first opposite)
    const uint64_t downfull = (uint64_t)Wse | ((uint64_t)Wdn << 32);
    const uint64_t upfull   = ((uint64_t)Wse << 32) | (uint64_t)Wup;
    const uint64_t Td = (downfull ^ (downfull >> 1)) &
                        (has_d ? 0x7FFFFFFFFFFFFFFFull : 0x000000007FFFFFFFull);
    const uint64_t Tu = (upfull ^ (upfull >> 1)) &
                        (has_u ? 0xFFFFFFFFFFFFFFFFull : 0xFFFFFFFF00000000ull);

    int dpx[RPB], tpx[RPB];
    #pragma unroll
    for (int r = 0; r < RPB; ++r) {
        const int p = p0 + r;               // <= 31 always
        const int i = i0 + r;
        const int t = (int)((Wse >> p) & 1u);

        const uint64_t zd = Td >> p;            // transitions at q >= p
        const uint64_t zu = Tu << (32 - p);     // transitions below row i
        int dd, du;
        if (zd) {
            dd = __ffsll((unsigned long long)zd);
        } else {                                // essentially never
            const uint32_t tm = t ? 0xFFFFFFFFu : 0u;
            dd = 1023;
            for (int ww = w + 2; ww < WR; ++ww) {
                const uint32_t Xw = vm[ww * WW + j] ^ tm;
                if (Xw) { dd = 32 * ww + (__ffs(Xw) - 1) - i; break; }
            }
        }
        if (zu) {
            du = __clzll((long long)zu) + 1;
        } else {                                // essentially never
            const uint32_t tm = t ? 0xFFFFFFFFu : 0u;
            du = 1023;
            for (int ww = w - 2; ww >= 0; --ww) {
                const uint32_t Xw = vm[ww * WW + j] ^ tm;
                if (Xw) { du = i - (32 * ww + 31 - __clz((int)Xw)); break; }
            }
        }
        dpx[r] = min(min(dd, du), 1023);
        tpx[r] = t;
    }

    // pack: pair-major uint4 per column, one ds_write_b128
    pk_s[j] = make_uint4(
        (uint32_t)((dpx[0] << 1) | tpx[0]) | ((uint32_t)((dpx[1] << 1) | tpx[1]) << 16),
        (uint32_t)((dpx[2] << 1) | tpx[2]) | ((uint32_t)((dpx[3] << 1) | tpx[3]) << 16),
        (uint32_t)((dpx[4] << 1) | tpx[4]) | ((uint32_t)((dpx[5] << 1) | tpx[5]) << 16),
        (uint32_t)((dpx[6] << 1) | tpx[6]) | ((uint32_t)((dpx[7] << 1) | tpx[7]) << 16));
    __syncthreads();

    // helper: fold one neighbor column (uint4) into all 8 rows' minima
    int mpx[RPB];
    #pragma unroll
    for (int r = 0; r < RPB; ++r) mpx[r] = dpx[r] * dpx[r];

    #define FOLD(COL, K2)                                                        \
        do {                                                                     \
            const uint4 _c = (COL);                                              \
            const uint32_t _w[4] = {_c.x, _c.y, _c.z, _c.w};                     \
            _Pragma("unroll")                                                    \
            for (int _pr = 0; _pr < NPAIR; ++_pr) {                              \
                const uint32_t _pk = _w[_pr];                                    \
                const int _e0 = ((int)(_pk & 1u) == tpx[2 * _pr])                \
                                    ? (int)((_pk & 0xFFFFu) >> 1) : 0;           \
                const int _e1 = ((int)((_pk >> 16) & 1u) == tpx[2 * _pr + 1])    \
                                    ? (int)(_pk >> 17) : 0;                      \
                mpx[2 * _pr]     = min(mpx[2 * _pr],     _e0 * _e0 + (K2));      \
                mpx[2 * _pr + 1] = min(mpx[2 * _pr + 1], _e1 * _e1 + (K2));      \
            }                                                                    \
        } while (0)

    // ---- Phase 2: k=1,2 unrolled — 4 ds_read_b128 total ----
    #pragma unroll
    for (int k = 1; k <= 2; ++k) {
        const int jl = j - k, jr = j + k;
        const uint4 pl  = pk_s[jl >= 0 ? jl : 0];
        const uint4 pr_ = pk_s[jr < WW ? jr : (WW - 1)];
        if (jl >= 0) FOLD(pl, k * k);
        if (jr < WW) FOLD(pr_, k * k);
    }

    // ---- merged exact tail over all 8 rows (P ~ 10%/wave, 1-2 iters) ----
    {
        int mx = mpx[0];
        #pragma unroll
        for (int r = 1; r < RPB; ++r) mx = max(mx, mpx[r]);
        const int kmaxRow = max(j, WW - 1 - j);
        for (int k = 3; k <= kmaxRow && k * k < mx; ++k) {
            const int k2 = k * k;
            if (k <= j)          FOLD(pk_s[j - k], k2);
            if (k <= WW - 1 - j) FOLD(pk_s[j + k], k2);
            mx = mpx[0];
            #pragma unroll
            for (int r = 1; r < RPB; ++r) mx = max(mx, mpx[r]);
        }
    }
    #undef FOLD

    // ---- Phase 3: loss terms ----
    float v = 0.0f;
    #pragma unroll
    for (int r = 0; r < RPB; ++r) {
        const float dt = __builtin_amdgcn_sqrtf((float)mpx[r]);
        float pr = __builtin_amdgcn_rcpf(1.0f + __expf(-xs[r]));
        pr = fminf(fmaxf(pr, 1e-7f), (float)(1.0 - 1e-7));
        v += pr * dt;
    }

    // ---- block reduction (512 threads = 8 waves), one per 4096 px ----
    #pragma unroll
    for (int off = 32; off > 0; off >>= 1)
        v += __shfl_down(v, off);

    const int lane = threadIdx.x & 63;
    const int wid  = threadIdx.x >> 6;
    if (lane == 0) sw[wid] = v;
    __syncthreads();
    if (threadIdx.x == 0) {
        float s = 0.0f;
        #pragma unroll
        for (int ww = 0; ww < 8; ++ww) s += sw[ww];
        partial[g] = s;
    }
}

// ---------------------------------------------------------------------------
// Deterministic final reduction of NGRP partials -> mean
// ---------------------------------------------------------------------------
__global__ __launch_bounds__(256) void finalreduce(
        const float* __restrict__ partial,
        float* __restrict__ out) {
    const float4 q = ((const float4*)partial)[threadIdx.x];   // 256*4 == 1024
    float v = (q.x + q.y) + (q.z + q.w);

    #pragma unroll
    for (int off = 32; off > 0; off >>= 1)
        v += __shfl_down(v, off);

    __shared__ float sw[4];
    const int lane = threadIdx.x & 63;
    const int wid  = threadIdx.x >> 6;
    if (lane == 0) sw[wid] = v;
    __syncthreads();
    if (threadIdx.x == 0)
        out[0] = ((sw[0] + sw[1]) + (sw[2] + sw[3])) * (1.0f / (float)NPIX);
}

extern "C" void kernel_launch(void* const* d_in, const int* in_sizes, int n_in,
                              void* d_out, int out_size, void* d_ws, size_t ws_size,
                              hipStream_t stream) {
    const float* logits  = (const float*)d_in[0];
    const float* targets = (const float*)d_in[1];
    float* out = (float*)d_out;

    // workspace layout: [ vmask u32 NWORDS (512KB) | partial float NGRP (4KB) ]
    uint32_t* vmask = (uint32_t*)d_ws;
    float* partial  = (float*)((char*)d_ws + (size_t)NWORDS * sizeof(uint32_t));

    packbits<<<NWORDS / 4 / 256, 256, 0, stream>>>(targets, vmask);
    fused_row8<<<NGRP, 512, 0, stream>>>(vmask, logits, partial);
    finalreduce<<<1, 256, 0, stream>>>(partial, out);
}